// Round 13
// baseline (95.840 us; speedup 1.0000x reference)
//
#include <hip/hip_runtime.h>

// Problem constants (fixed by setup_inputs).
constexpr int L  = 512;   // sequence length
constexpr int CS = 384;   // c_s
constexpr int CH = 32;    // c_h
constexpr int CZ = 128;   // c_z
constexpr float LN_EPS = 1e-5f;

typedef float f2 __attribute__((ext_vector_type(2)));
typedef float f4 __attribute__((ext_vector_type(4)));

// ---------------------------------------------------------------------------
// Kernel 0 (DIAGNOSTIC): zero all of d_out using fillBuffer's exact pattern —
// each block owns a 128 KB CONTIGUOUS region and sweeps it linearly (4 KB
// per block-step). d_out is fully overwritten by k_main afterwards, so
// correctness is unaffected. The total-dur delta over R11's 76.9 us reads
// d_out's linear-write bandwidth directly:
//   +~21 us  -> d_out sustains ~6.6 TB/s linear (pattern was our problem)
//   +~75 us  -> d_out is a ~1.8 TB/s wall for every pattern (roofline).
// ---------------------------------------------------------------------------
__global__ __launch_bounds__(256) void k_prefill(float* __restrict__ out)
{
    const size_t base = (size_t)blockIdx.x * (256 * 32 * 4) + threadIdx.x * 4;
    f4 zero = 0.f;
#pragma unroll 8
    for (int k = 0; k < 32; ++k)
        *(f4*)(out + base + (size_t)k * 1024) = zero;
}

// ---------------------------------------------------------------------------
// Kernel 1 (v2): LayerNorm + dual projection + mask.  (R11-exact)
// ---------------------------------------------------------------------------
__global__ __launch_bounds__(64) void k_ln_proj(
    const float* __restrict__ s, const int* __restrict__ mask,
    const float* __restrict__ ln_scale, const float* __restrict__ ln_bias,
    const float* __restrict__ w1, const float* __restrict__ b1,
    const float* __restrict__ w2, const float* __restrict__ b2,
    float* __restrict__ a, float* __restrict__ b)
{
    __shared__ float sn_lds[CS];
    const int lane = threadIdx.x;
    const int row  = blockIdx.x;

    const float* srow = s + row * CS;
    float v[6];
    float sum = 0.f, sumsq = 0.f;
#pragma unroll
    for (int q = 0; q < 6; ++q) {
        v[q] = srow[lane + 64 * q];
        sum   += v[q];
        sumsq += v[q] * v[q];
    }
#pragma unroll
    for (int off = 32; off; off >>= 1) {
        sum   += __shfl_xor(sum, off);
        sumsq += __shfl_xor(sumsq, off);
    }
    const float mu   = sum * (1.f / CS);
    const float var  = sumsq * (1.f / CS) - mu * mu;
    const float rstd = rsqrtf(var + LN_EPS);
#pragma unroll
    for (int q = 0; q < 6; ++q) {
        const int k = lane + 64 * q;
        sn_lds[k] = (v[q] - mu) * rstd * ln_scale[k] + ln_bias[k];
    }
    __syncthreads();

    const int c    = lane & 31;
    const int half = lane >> 5;
    const float* W  = half ? w2 : w1;
    const float* Bv = half ? b2 : b1;
    float acc = 0.f;
#pragma unroll 4
    for (int k = 0; k < CS; ++k)
        acc += sn_lds[k] * W[k * CH + c];
    const float m = (float)mask[row];
    const float outv = (acc + Bv[c]) * m;
    (half ? b : a)[row * CH + c] = outv;
}

// ---------------------------------------------------------------------------
// Kernel 2 (v2): T[j][c][z] = sum_e b[j][e] * w_out[...].  (R11-exact)
// ---------------------------------------------------------------------------
__global__ __launch_bounds__(512) void k_T(
    const float* __restrict__ b, const float* __restrict__ w_out,
    float* __restrict__ T)
{
    const int j0  = blockIdx.x * 2;
    const int t   = threadIdx.x;
    const int c   = t >> 4;            // 0..31
    const int zo  = t & 15;            // z-octet: z = 8*zo .. 8*zo+7

    float bj0[CH], bj1[CH];
#pragma unroll
    for (int e = 0; e < CH; ++e) {
        bj0[e] = b[j0 * CH + e];       // wave-uniform -> broadcast
        bj1[e] = b[(j0 + 1) * CH + e];
    }

    const float* wbase = w_out + (size_t)(c * CH) * CZ + 8 * zo;
    f4 a00 = 0.f, a01 = 0.f, a10 = 0.f, a11 = 0.f;
#pragma unroll
    for (int e = 0; e < CH; ++e) {
        const f4 w0 = *(const f4*)(wbase + e * CZ);
        const f4 w1 = *(const f4*)(wbase + e * CZ + 4);
        a00 += bj0[e] * w0;  a01 += bj0[e] * w1;
        a10 += bj1[e] * w0;  a11 += bj1[e] * w1;
    }

    float* Tp0 = T + (size_t)j0 * (CH * CZ) + c * CZ + 8 * zo;
    *(f4*)(Tp0)     = a00;
    *(f4*)(Tp0 + 4) = a01;
    float* Tp1 = Tp0 + CH * CZ;
    *(f4*)(Tp1)     = a10;
    *(f4*)(Tp1 + 4) = a11;
}

// ---------------------------------------------------------------------------
// Kernel 3: z[i,j,:] = a[i,:] @ T[j,:,:] + b_out.  (R11-exact, 76.9 us pass)
// ---------------------------------------------------------------------------
__global__ __launch_bounds__(512) void k_main(
    const float* __restrict__ a, const float* __restrict__ T,
    const float* __restrict__ b_out, float* __restrict__ out)
{
    __shared__ float a_lds[64][CH];    // 8 KB

    const int bid = blockIdx.x;
    const int j0  = (bid & 63) * 8;
    const int i0  = (bid >> 6) * 64;
    const int t   = threadIdx.x;
    const int wave = t >> 6;
    const int lane = t & 63;
    const int j    = j0 + wave;

    // Stage a-tile: 2048 floats, 512 threads x float4.
    ((float4*)a_lds)[t] = ((const float4*)(a + (size_t)i0 * CH))[t];

    // T[j] column pair for this lane: 64 VGPRs.
    float2 T_reg[CH];
    const float* Tj = T + (size_t)j * (CH * CZ) + 2 * lane;
#pragma unroll
    for (int c = 0; c < CH; ++c)
        T_reg[c] = *(const float2*)(Tj + c * CZ);

    const float2 bo = *(const float2*)&b_out[2 * lane];
    float* outp = out + (size_t)i0 * L * CZ + (size_t)j * CZ + 2 * lane;

    __syncthreads();

#pragma unroll 2
    for (int ii = 0; ii < 64; ++ii) {
        const float4* ap = (const float4*)&a_lds[ii][0];
        float av[CH];
#pragma unroll
        for (int q = 0; q < 8; ++q) {
            const float4 tmp = ap[q];
            av[4 * q + 0] = tmp.x;
            av[4 * q + 1] = tmp.y;
            av[4 * q + 2] = tmp.z;
            av[4 * q + 3] = tmp.w;
        }
        float ax = 0.f, ay = 0.f;
#pragma unroll
        for (int c = 0; c < CH; ++c) {
            ax += av[c] * T_reg[c].x;
            ay += av[c] * T_reg[c].y;
        }
        f2 o;
        o.x = ax + bo.x;
        o.y = ay + bo.y;
        __builtin_nontemporal_store(o, (f2*)(outp + (size_t)ii * L * CZ));
    }
}

// ---------------------------------------------------------------------------
extern "C" void kernel_launch(void* const* d_in, const int* in_sizes, int n_in,
                              void* d_out, int out_size, void* d_ws, size_t ws_size,
                              hipStream_t stream) {
    const float* s        = (const float*)d_in[0];
    const int*   mask     = (const int*)d_in[1];
    const float* ln_scale = (const float*)d_in[2];
    const float* ln_bias  = (const float*)d_in[3];
    const float* w1       = (const float*)d_in[4];
    const float* b1       = (const float*)d_in[5];
    const float* w2       = (const float*)d_in[6];
    const float* b2       = (const float*)d_in[7];
    const float* w_out    = (const float*)d_in[8];
    const float* b_out    = (const float*)d_in[9];
    float* out = (float*)d_out;

    // Workspace: a [512*32], b [512*32], T [512*32*128]  (8.125 MB total).
    float* a = (float*)d_ws;
    float* b = a + L * CH;
    float* T = b + L * CH;

    // Diagnostic linear prefill of d_out (overwritten by k_main below).
    k_prefill<<<1024, 256, 0, stream>>>(out);
    k_ln_proj<<<L, 64, 0, stream>>>(s, mask, ln_scale, ln_bias,
                                    w1, b1, w2, b2, a, b);
    k_T<<<L / 2, 512, 0, stream>>>(b, w_out, T);
    k_main<<<512, 512, 0, stream>>>(a, T, b_out, out);
}